// Round 11
// baseline (120.918 us; speedup 1.0000x reference)
//
#include <hip/hip_runtime.h>

#define NROWS 100000
#define IN_DIM 512

typedef __attribute__((ext_vector_type(8))) short short8;
typedef __attribute__((ext_vector_type(4))) float f32x4;
typedef unsigned int u32;
typedef const __attribute__((address_space(1))) u32* gptr_t;
typedef __attribute__((address_space(3))) u32* lptr_t;

__device__ inline unsigned short f2bf(float f) {
    union { float f; unsigned u; } v; v.f = f;
    unsigned u = v.u;
    return (unsigned short)((u + 0x7FFFu + ((u >> 16) & 1u)) >> 16);
}

// Prepack: B-fragments (bf16) in exact MFMA lane order + fused que bias.
// B = [80 cols x 512 k]: cols 0..63 = Wv, 64..71 = Wq@Wk, 72..79 = 0.
// Bp layout: [t(5)][ks(16)][lane(64)][e(8)] bf16; col = t*16+(lane&15),
// k = ks*32 + (lane>>4)*8 + e.
__global__ void qg_prepack(const float* __restrict__ Wk, const float* __restrict__ bk,
                           const float* __restrict__ Wq, const float* __restrict__ bq,
                           const float* __restrict__ Wv,
                           unsigned short* __restrict__ Bp, float* __restrict__ qb) {
    int id = blockIdx.x * 256 + threadIdx.x;  // 0..5119
    if (id < 8) {
        float s = bq[id];
        #pragma unroll 4
        for (int j = 0; j < 100; ++j) s += Wq[id * 100 + j] * bk[j];
        qb[id] = s;
    }
    if (id >= 5120) return;
    int lane = id & 63;
    int ks = (id >> 6) & 15;
    int t = id >> 10;
    int c = t * 16 + (lane & 15);
    int kk = ks * 32 + (lane >> 4) * 8;
    short8 pk;
    #pragma unroll
    for (int e = 0; e < 8; ++e) {
        int k2 = kk + e;
        float w;
        if (c < 64) {
            w = Wv[c * IN_DIM + k2];
        } else if (c < 72) {
            float s = 0.f;
            #pragma unroll 4
            for (int j = 0; j < 100; ++j) s += Wq[(c - 64) * 100 + j] * Wk[j * IN_DIM + k2];
            w = s;
        } else {
            w = 0.f;
        }
        pk[e] = (short)f2bf(w);
    }
    ((short8*)Bp)[id] = pk;
}

// Main: 128 threads = 2 waves, 16 rows/wave, grid 3125 (exact: 3125*32=100000).
// ALL VMEM is global_load_lds (zero VGPR destinations -> regalloc-proof depth):
//   - B (80 KB) preloaded to LDS once per block (40 instrs/wave, L2-hot)
//   - A tile staged as 32 SEQUENTIAL 1KB instrs covering one contiguous 32KB
//     region (m13-copy access shape; XOR swizzle inside 128B groups only)
// Ladder: vmcnt(32) [B done] -> s_barrier -> vmcnt(0) [tile done] -> pure-LDS
// compute (zero VMEM in K-loop). NT stores for out.
__global__ __launch_bounds__(128, 1) void qg_main(const float* __restrict__ x,
                                                  const float* __restrict__ bv,
                                                  const unsigned short* __restrict__ Bp,
                                                  const float* __restrict__ qb,
                                                  float* __restrict__ out) {
    __shared__ float smem[36864];       // 144 KB: [0,20480) B ; +w*8192 tiles
    const int tid = threadIdx.x;
    const int w = tid >> 6;
    const int lane = tid & 63;
    const int g = lane >> 4;            // k sub-block (k = g*8+e within a step)
    const int cl = lane & 15;           // row-within-tile / col-within-tile
    const int rowbase = (blockIdx.x * 2 + w) * 16;

    float* Bls = smem;                  // 20480 floats = 80 KB
    float* tile = smem + 20480 + w * 8192;   // 32 KB per wave

    // Bias preload — settled before the hand-counted VMEM region.
    float bvr[4];
    #pragma unroll
    for (int t = 0; t < 4; ++t) bvr[t] = bv[t * 16 + cl];
    float qbr = qb[cl & 7];
    asm volatile("s_waitcnt vmcnt(0)" ::: "memory");

    // ---- B preload: each wave loads its 40 KB half (40 x 1KB, L2-hot) ----
    #pragma unroll
    for (int j = 0; j < 40; ++j) {
        const int slot = w * 2560 + j * 64;     // 16B-slot index (uniform part)
        const char* src = (const char*)Bp + ((size_t)(slot + lane)) * 16;
        __builtin_amdgcn_global_load_lds((gptr_t)(const void*)src,
                                         (lptr_t)(void*)(Bls + (size_t)slot * 4), 16, 0, 0);
    }
    __builtin_amdgcn_sched_barrier(0);

    // ---- A burst: 32 sequential 1KB loads covering rows [rowbase, +16) ----
    // LDS slot S = i*64+lane (16B units): row = S>>7, c' = S&127.
    // Stored chunk c' holds x chunk c = c' ^ (row&7) (bank swizzle, 128B-local).
    #pragma unroll
    for (int i = 0; i < 32; ++i) {
        const int row = i >> 1;
        const int c = (((i & 1) * 64) + lane) ^ (row & 7);
        const float* src = x + (size_t)(rowbase + row) * IN_DIM + c * 4;
        __builtin_amdgcn_global_load_lds((gptr_t)(const void*)src,
                                         (lptr_t)(void*)(tile + i * 256), 16, 0, 0);
    }
    __builtin_amdgcn_sched_barrier(0);

    asm volatile("s_waitcnt vmcnt(32)" ::: "memory");   // all B done, A in flight
    __builtin_amdgcn_s_barrier();                        // B visible to both waves
    asm volatile("s_waitcnt vmcnt(0)" ::: "memory");    // tile done
    __builtin_amdgcn_sched_barrier(0);

    // ---- Pure-LDS K-loop: 16 steps x (2 A ds_read + 5 B ds_read + 5 MFMA) ----
    f32x4 acc[5];
    #pragma unroll
    for (int t = 0; t < 5; ++t) acc[t] = (f32x4){0.f, 0.f, 0.f, 0.f};
    const float4* t4 = (const float4*)tile;
    const short8* b8 = (const short8*)Bls;

    #pragma unroll
    for (int s = 0; s < 16; ++s) {
        const int c0 = (s * 8 + g * 2)     ^ (cl & 7);
        const int c1 = (s * 8 + g * 2 + 1) ^ (cl & 7);
        float4 f0 = t4[cl * 128 + c0];
        float4 f1 = t4[cl * 128 + c1];
        short8 af;
        af[0] = (short)f2bf(f0.x); af[1] = (short)f2bf(f0.y);
        af[2] = (short)f2bf(f0.z); af[3] = (short)f2bf(f0.w);
        af[4] = (short)f2bf(f1.x); af[5] = (short)f2bf(f1.y);
        af[6] = (short)f2bf(f1.z); af[7] = (short)f2bf(f1.w);
        #pragma unroll
        for (int t = 0; t < 5; ++t)
            acc[t] = __builtin_amdgcn_mfma_f32_16x16x32_bf16(af, b8[(t * 16 + s) * 64 + lane], acc[t], 0, 0, 0);
    }

    // ---- Per-wave epilogue in the (now dead) tile region ----
    asm volatile("s_waitcnt lgkmcnt(0)" ::: "memory");
    float (*vld)[68] = (float(*)[68])tile;               // 16 x 68 floats
    float (*wld)[8]  = (float(*)[8])(tile + 16 * 68);    // 16 x 8 floats
    // C layout: col = lane&15, row = (lane>>4)*4 + reg (verified m89).
    #pragma unroll
    for (int t = 0; t < 4; ++t) {
        #pragma unroll
        for (int r = 0; r < 4; ++r)
            vld[g * 4 + r][t * 16 + cl] = acc[t][r] + bvr[t];
    }
    if (cl < 8) {
        #pragma unroll
        for (int r = 0; r < 4; ++r)
            wld[g * 4 + r][cl] = acc[4][r] + qbr;
    }
    asm volatile("s_waitcnt lgkmcnt(0)" ::: "memory");

    // Softmax over the 8 que values: lanes 0..15 each own one row.
    if (lane < 16) {
        float q[8];
        float m = -1e30f;
        #pragma unroll
        for (int k = 0; k < 8; ++k) { q[k] = wld[lane][k]; m = fmaxf(m, q[k]); }
        float ssum = 0.f;
        #pragma unroll
        for (int k = 0; k < 8; ++k) { q[k] = __expf(q[k] - m); ssum += q[k]; }
        float inv = 1.f / ssum;
        #pragma unroll
        for (int k = 0; k < 8; ++k) wld[lane][k] = q[k] * inv;
    }
    asm volatile("s_waitcnt lgkmcnt(0)" ::: "memory");

    // Coalesced NONTEMPORAL output: out[row][k][v] = w[k] * val[v];
    // per-instr = contiguous 1 KB.
    f32x4* outp = (f32x4*)out + (size_t)rowbase * 128;
    #pragma unroll
    for (int it = 0; it < 32; ++it) {
        int idx = it * 64 + lane;
        int row = idx >> 7;             // 0..15
        int j = idx & 127;              // float4 index within 512-float out row
        float wgt = wld[row][j >> 4];
        float4 vv = *(const float4*)&vld[row][(j & 15) * 4];
        f32x4 o;
        o[0] = wgt * vv.x; o[1] = wgt * vv.y; o[2] = wgt * vv.z; o[3] = wgt * vv.w;
        __builtin_nontemporal_store(o, &outp[(size_t)row * 128 + j]);
    }
}

extern "C" void kernel_launch(void* const* d_in, const int* in_sizes, int n_in,
                              void* d_out, int out_size, void* d_ws, size_t ws_size,
                              hipStream_t stream) {
    const float* x  = (const float*)d_in[0];
    const float* Wk = (const float*)d_in[1];
    const float* bk = (const float*)d_in[2];
    const float* Wq = (const float*)d_in[3];
    const float* bq = (const float*)d_in[4];
    const float* Wv = (const float*)d_in[5];
    const float* bv = (const float*)d_in[6];
    float* out = (float*)d_out;

    unsigned short* Bp = (unsigned short*)d_ws;          // 81920 B
    float* qb = (float*)((char*)d_ws + 81920);           // 8 floats

    qg_prepack<<<20, 256, 0, stream>>>(Wk, bk, Wq, bq, Wv, Bp, qb);
    qg_main<<<3125, 128, 0, stream>>>(x, bv, Bp, qb, out);
}

// Round 12
// 101.974 us; speedup vs baseline: 1.1858x; 1.1858x over previous
//
#include <hip/hip_runtime.h>

#define NROWS 100000
#define IN_DIM 512

typedef __attribute__((ext_vector_type(8))) short short8;
typedef __attribute__((ext_vector_type(4))) float f32x4;

__device__ inline unsigned short f2bf(float f) {
    union { float f; unsigned u; } v; v.f = f;
    unsigned u = v.u;
    return (unsigned short)((u + 0x7FFFu + ((u >> 16) & 1u)) >> 16);
}

// Prepack: B-fragments (bf16) in exact MFMA lane order + fused que bias.
// B = [80 cols x 512 k]: cols 0..63 = Wv, 64..71 = Wq@Wk, 72..79 = 0.
// Bp layout: [t(5)][ks(16)][lane(64)][e(8)] bf16; col = t*16+(lane&15),
// k = ks*32 + (lane>>4)*8 + e.
__global__ void qg_prepack(const float* __restrict__ Wk, const float* __restrict__ bk,
                           const float* __restrict__ Wq, const float* __restrict__ bq,
                           const float* __restrict__ Wv,
                           unsigned short* __restrict__ Bp, float* __restrict__ qb) {
    int id = blockIdx.x * 256 + threadIdx.x;  // 0..5119
    if (id < 8) {
        float s = bq[id];
        #pragma unroll 4
        for (int j = 0; j < 100; ++j) s += Wq[id * 100 + j] * bk[j];
        qb[id] = s;
    }
    if (id >= 5120) return;
    int lane = id & 63;
    int ks = (id >> 6) & 15;
    int t = id >> 10;
    int c = t * 16 + (lane & 15);
    int kk = ks * 32 + (lane >> 4) * 8;
    short8 pk;
    #pragma unroll
    for (int e = 0; e < 8; ++e) {
        int k2 = kk + e;
        float w;
        if (c < 64) {
            w = Wv[c * IN_DIM + k2];
        } else if (c < 72) {
            float s = 0.f;
            #pragma unroll 4
            for (int j = 0; j < 100; ++j) s += Wq[(c - 64) * 100 + j] * Wk[j * IN_DIM + k2];
            w = s;
        } else {
            w = 0.f;
        }
        pk[e] = (short)f2bf(w);
    }
    ((short8*)Bp)[id] = pk;
}

// Main: 256 threads = 4 independent waves, 16 rows/wave, no barriers.
// Main-loop VMEM is inline-asm global_load_dwordx4 with a hand-counted vmcnt
// ladder. Output stores are inline-asm with sc0 sc1 nt: force the write
// stream past L2/MALL so x stays L3-resident across replays.
__global__ __launch_bounds__(256, 2) void qg_main(const float* __restrict__ x,
                                                  const float* __restrict__ bv,
                                                  const unsigned short* __restrict__ Bp,
                                                  const float* __restrict__ qb,
                                                  float* __restrict__ out) {
    __shared__ float vlds[4][16][68];
    __shared__ float wlds[4][16][8];
    const int tid = threadIdx.x;
    const int w = tid >> 6;
    const int lane = tid & 63;
    const int g = lane >> 4;       // k sub-block (k = g*8+e within a 32-K step)
    const int cl = lane & 15;      // A row within tile / B col within tile
    const int rowbase = blockIdx.x * 64 + w * 16;   // 1563*64 = 100032 covers N
    const int arow = min(rowbase + cl, NROWS - 1);

    const unsigned voffA = (unsigned)(arow * 512 + g * 8) * 4u;  // byte off in x
    const unsigned voffB = (unsigned)lane * 16u;                 // byte off in Bp

    // Bias preload — completed (vmcnt(0)) before the asm region so the
    // compiler's waitcnt model never overlaps the hand-counted FIFO.
    float bvr[4];
    #pragma unroll
    for (int t = 0; t < 4; ++t) bvr[t] = bv[t * 16 + cl];
    float qbr = qb[cl & 7];
    asm volatile("s_waitcnt vmcnt(0)" ::: "memory");

    f32x4 A0[4], A1[4];      // A ring: 2 x dwordx4 per step
    short8 Bv[4][5];         // B ring: 5 x dwordx4 per step
    f32x4 acc[5];
    #pragma unroll
    for (int t = 0; t < 5; ++t) acc[t] = (f32x4){0.f, 0.f, 0.f, 0.f};

#define GLD(dst, off, base, IMM)                                               \
    asm volatile("global_load_dwordx4 %0, %1, %2 offset:" IMM                  \
                 : "=&v"(dst) : "v"(off), "s"(base) : "memory")

#define ISSUE(S) do {                                                          \
        unsigned va_ = voffA + (S) * 128u;                                     \
        GLD(A0[(S) & 3], va_, x, "0");                                         \
        GLD(A1[(S) & 3], va_, x, "16");                                        \
        GLD(Bv[(S) & 3][0], voffB + (0 * 16 + (S)) * 1024u, Bp, "0");          \
        GLD(Bv[(S) & 3][1], voffB + (1 * 16 + (S)) * 1024u, Bp, "0");          \
        GLD(Bv[(S) & 3][2], voffB + (2 * 16 + (S)) * 1024u, Bp, "0");          \
        GLD(Bv[(S) & 3][3], voffB + (3 * 16 + (S)) * 1024u, Bp, "0");          \
        GLD(Bv[(S) & 3][4], voffB + (4 * 16 + (S)) * 1024u, Bp, "0");          \
    } while (0)

#define CONSUME(S, NW) do {                                                    \
        asm volatile("s_waitcnt vmcnt(" NW ")" ::: "memory");                  \
        __builtin_amdgcn_sched_barrier(0);                                     \
        f32x4 f0_ = A0[(S) & 3];                                               \
        f32x4 f1_ = A1[(S) & 3];                                               \
        short8 af_;                                                            \
        af_[0] = (short)f2bf(f0_[0]); af_[1] = (short)f2bf(f0_[1]);            \
        af_[2] = (short)f2bf(f0_[2]); af_[3] = (short)f2bf(f0_[3]);            \
        af_[4] = (short)f2bf(f1_[0]); af_[5] = (short)f2bf(f1_[1]);            \
        af_[6] = (short)f2bf(f1_[2]); af_[7] = (short)f2bf(f1_[3]);            \
        acc[0] = __builtin_amdgcn_mfma_f32_16x16x32_bf16(af_, Bv[(S)&3][0], acc[0], 0, 0, 0); \
        acc[1] = __builtin_amdgcn_mfma_f32_16x16x32_bf16(af_, Bv[(S)&3][1], acc[1], 0, 0, 0); \
        acc[2] = __builtin_amdgcn_mfma_f32_16x16x32_bf16(af_, Bv[(S)&3][2], acc[2], 0, 0, 0); \
        acc[3] = __builtin_amdgcn_mfma_f32_16x16x32_bf16(af_, Bv[(S)&3][3], acc[3], 0, 0, 0); \
        acc[4] = __builtin_amdgcn_mfma_f32_16x16x32_bf16(af_, Bv[(S)&3][4], acc[4], 0, 0, 0); \
    } while (0)

    // Prologue: 3 batches (21 loads) in flight.
    ISSUE(0); ISSUE(1); ISSUE(2);
    // Steady state: consume s (vmcnt(14): batches s+1,s+2 may remain), issue s+3.
    CONSUME(0, "14");  ISSUE(3);
    CONSUME(1, "14");  ISSUE(4);
    CONSUME(2, "14");  ISSUE(5);
    CONSUME(3, "14");  ISSUE(6);
    CONSUME(4, "14");  ISSUE(7);
    CONSUME(5, "14");  ISSUE(8);
    CONSUME(6, "14");  ISSUE(9);
    CONSUME(7, "14");  ISSUE(10);
    CONSUME(8, "14");  ISSUE(11);
    CONSUME(9, "14");  ISSUE(12);
    CONSUME(10, "14"); ISSUE(13);
    CONSUME(11, "14"); ISSUE(14);
    CONSUME(12, "14"); ISSUE(15);
    CONSUME(13, "14");
    CONSUME(14, "7");
    CONSUME(15, "0");
#undef GLD
#undef ISSUE
#undef CONSUME

    // ---- Per-wave epilogue (intra-wave lockstep; lgkmcnt ordering only) ----
    // C layout: col = lane&15, row = (lane>>4)*4 + reg  (verified m89).
    #pragma unroll
    for (int t = 0; t < 4; ++t) {
        #pragma unroll
        for (int r = 0; r < 4; ++r)
            vlds[w][g * 4 + r][t * 16 + cl] = acc[t][r] + bvr[t];
    }
    if (cl < 8) {
        #pragma unroll
        for (int r = 0; r < 4; ++r)
            wlds[w][g * 4 + r][cl] = acc[4][r] + qbr;
    }
    asm volatile("s_waitcnt lgkmcnt(0)" ::: "memory");

    // Softmax over the 8 que values: lanes 0..15 each own one row.
    if (lane < 16) {
        float q[8];
        float m = -1e30f;
        #pragma unroll
        for (int k = 0; k < 8; ++k) { q[k] = wlds[w][lane][k]; m = fmaxf(m, q[k]); }
        float ssum = 0.f;
        #pragma unroll
        for (int k = 0; k < 8; ++k) { q[k] = __expf(q[k] - m); ssum += q[k]; }
        float inv = 1.f / ssum;
        #pragma unroll
        for (int k = 0; k < 8; ++k) wlds[w][lane][k] = q[k] * inv;
    }
    asm volatile("s_waitcnt lgkmcnt(0)" ::: "memory");

    // Coalesced STREAMING output (sc0 sc1 nt — bypass L2/MALL):
    // out[row][k][v] = w[k] * val[v]; per-instr = contiguous 1 KB.
    #pragma unroll
    for (int it = 0; it < 32; ++it) {
        int idx = it * 64 + lane;
        int row = idx >> 7;             // 0..15
        int j = idx & 127;              // float4 index within 512-float out row
        if (rowbase + row < NROWS) {
            float wgt = wlds[w][row][j >> 4];
            float4 vv = *(const float4*)&vlds[w][row][(j & 15) * 4];
            f32x4 o;
            o[0] = wgt * vv.x; o[1] = wgt * vv.y; o[2] = wgt * vv.z; o[3] = wgt * vv.w;
            unsigned ob = (unsigned)(((rowbase + row) * 512 + j * 4) * 4);
            asm volatile("global_store_dwordx4 %0, %1, %2 sc0 sc1 nt"
                         :: "v"(ob), "v"(o), "s"(out) : "memory");
        }
    }
}

extern "C" void kernel_launch(void* const* d_in, const int* in_sizes, int n_in,
                              void* d_out, int out_size, void* d_ws, size_t ws_size,
                              hipStream_t stream) {
    const float* x  = (const float*)d_in[0];
    const float* Wk = (const float*)d_in[1];
    const float* bk = (const float*)d_in[2];
    const float* Wq = (const float*)d_in[3];
    const float* bq = (const float*)d_in[4];
    const float* Wv = (const float*)d_in[5];
    const float* bv = (const float*)d_in[6];
    float* out = (float*)d_out;

    unsigned short* Bp = (unsigned short*)d_ws;          // 81920 B
    float* qb = (float*)((char*)d_ws + 81920);           // 8 floats

    qg_prepack<<<20, 256, 0, stream>>>(Wk, bk, Wq, bq, Wv, Bp, qb);
    qg_main<<<1563, 256, 0, stream>>>(x, bv, Bp, qb, out);
}